// Round 1
// baseline (9572.901 us; speedup 1.0000x reference)
//
#include <hip/hip_runtime.h>

#define NEG_SLOPE 0.2f

// Initialize h_pos/h_neg accumulators to broadcast bias; zero softmax denoms.
__global__ void init_kernel(float* __restrict__ out_hpos, float* __restrict__ out_hneg,
                            const float* __restrict__ b_pos, const float* __restrict__ b_neg,
                            float* __restrict__ s_pos, float* __restrict__ s_neg, int n) {
    int i = blockIdx.x * blockDim.x + threadIdx.x;
    int total = n * 128;
    if (i < total) {
        int c = i & 127;
        out_hpos[i] = b_pos[c];
        out_hneg[i] = b_neg[c];
    }
    if (i < n * 8) { s_pos[i] = 0.f; s_neg[i] = 0.f; }
}

// Register-blocked fp32 SGEMM: out[n_rows, BN] = op(X[n_rows, KDIM] @ W[KDIM, BN] + bias)
// BM=128 rows/block, 8x8 outputs/thread. CONCAT: k<128 from X, else X2 (both stride 128).
template<int KDIM, int BN, bool CONCAT, bool RELU>
__global__ __launch_bounds__(BN * 2)
void sgemm_kernel(const float* __restrict__ X, const float* __restrict__ X2,
                  const float* __restrict__ W, const float* __restrict__ bias,
                  float* __restrict__ out, int n_rows) {
    constexpr int BM = 128, BK = 8;
    constexpr int NT = BN * 2;
    __shared__ float Xs[BK][BM];
    __shared__ float Ws[BK][BN];
    const int tid = threadIdx.x;
    const int tx = tid % (BN / 8);
    const int ty = tid / (BN / 8);
    const int row0 = blockIdx.x * BM;

    float acc[8][8];
#pragma unroll
    for (int i = 0; i < 8; i++)
#pragma unroll
        for (int j = 0; j < 8; j++) acc[i][j] = 0.f;

    for (int kb = 0; kb < KDIM / BK; ++kb) {
        // Stage X tile (BM x BK), transposed into Xs[k][r]
#pragma unroll
        for (int u = 0; u < (BM * BK) / (NT * 4); ++u) {
            int f = (tid + u * NT) * 4;
            int r = f >> 3;
            int c = f & 7;
            int gr = row0 + r;
            if (gr >= n_rows) gr = n_rows - 1;
            int k = kb * BK + c;
            const float* src;
            if (CONCAT) src = (k < 128) ? (X + (size_t)gr * 128 + k)
                                        : (X2 + (size_t)gr * 128 + (k - 128));
            else        src = X + (size_t)gr * KDIM + k;
            float4 v = *(const float4*)src;
            Xs[c + 0][r] = v.x; Xs[c + 1][r] = v.y;
            Xs[c + 2][r] = v.z; Xs[c + 3][r] = v.w;
        }
        // Stage W tile (BK x BN)
        {
            int f = tid * 4;
            int k = f / BN;
            int col = f % BN;
            float4 v = *(const float4*)(W + (size_t)(kb * BK + k) * BN + col);
            *(float4*)&Ws[k][col] = v;
        }
        __syncthreads();
#pragma unroll
        for (int kk = 0; kk < BK; ++kk) {
            float x[8], w[8];
            *(float4*)&x[0] = *(const float4*)&Xs[kk][ty * 8];
            *(float4*)&x[4] = *(const float4*)&Xs[kk][ty * 8 + 4];
            *(float4*)&w[0] = *(const float4*)&Ws[kk][tx * 8];
            *(float4*)&w[4] = *(const float4*)&Ws[kk][tx * 8 + 4];
#pragma unroll
            for (int i = 0; i < 8; i++)
#pragma unroll
                for (int j = 0; j < 8; j++) acc[i][j] = fmaf(x[i], w[j], acc[i][j]);
        }
        __syncthreads();
    }
    // Epilogue
#pragma unroll
    for (int i = 0; i < 8; i++) {
        int r = row0 + ty * 8 + i;
        if (r < n_rows) {
#pragma unroll
            for (int j0 = 0; j0 < 8; j0 += 4) {
                float vv[4];
#pragma unroll
                for (int j = 0; j < 4; j++) {
                    float t = acc[i][j0 + j];
                    if (bias) t += bias[tx * 8 + j0 + j];
                    if (RELU) t = t > 0.f ? t : 0.f;
                    vv[j] = t;
                }
                float4 v; v.x = vv[0]; v.y = vv[1]; v.z = vv[2]; v.w = vv[3];
                *(float4*)(out + (size_t)r * BN + tx * 8 + j0) = v;
            }
        }
    }
}

// el[n,h] = dot(feat[n,h,:], al[h,:]);  er likewise.  idx = n*8+h; feat offset = idx*16.
__global__ void eler_kernel(const float* __restrict__ feat, const float* __restrict__ al,
                            const float* __restrict__ ar, float* __restrict__ el,
                            float* __restrict__ er, int n) {
    int idx = blockIdx.x * blockDim.x + threadIdx.x;
    if (idx >= n * 8) return;
    int h = idx & 7;
    const float4* f = (const float4*)(feat + (size_t)idx * 16);
    const float4* a = (const float4*)(al + h * 16);
    const float4* b = (const float4*)(ar + h * 16);
    float sl = 0.f, sr = 0.f;
#pragma unroll
    for (int q = 0; q < 4; q++) {
        float4 fv = f[q], av = a[q], bv = b[q];
        sl += fv.x * av.x + fv.y * av.y + fv.z * av.z + fv.w * av.w;
        sr += fv.x * bv.x + fv.y * bv.y + fv.z * bv.z + fv.w * bv.w;
    }
    el[idx] = sl; er[idx] = sr;
}

// Pass 1 over edges: accumulate softmax denominators (no max-shift; logits bounded).
__global__ void edge_s_kernel(const int* __restrict__ src, const int* __restrict__ dst,
                              const float* __restrict__ el, const float* __restrict__ er,
                              float* __restrict__ s, int ne) {
    int e = blockIdx.x * blockDim.x + threadIdx.x;
    if (e >= ne) return;
    int si = src[e], di = dst[e];
    const float4* l = (const float4*)(el + (size_t)si * 8);
    const float4* r = (const float4*)(er + (size_t)di * 8);
    float4 l0 = l[0], l1 = l[1], r0 = r[0], r1 = r[1];
    float ev[8] = {l0.x + r0.x, l0.y + r0.y, l0.z + r0.z, l0.w + r0.w,
                   l1.x + r1.x, l1.y + r1.y, l1.z + r1.z, l1.w + r1.w};
#pragma unroll
    for (int h = 0; h < 8; h++) {
        float x = ev[h];
        x = x < 0.f ? NEG_SLOPE * x : x;
        atomicAdd(&s[(size_t)di * 8 + h], __expf(x));
    }
}

// Pass 2: a = exp(lrelu(el[src]+er[dst]))/s[dst]; scatter a*feat[src] into out[dst].
// One thread per (edge, head).
__global__ void edge_acc_kernel(const int* __restrict__ src, const int* __restrict__ dst,
                                const float* __restrict__ el, const float* __restrict__ er,
                                const float* __restrict__ s, const float* __restrict__ feat,
                                float* __restrict__ outh, int ne) {
    int t = blockIdx.x * blockDim.x + threadIdx.x;
    if (t >= ne * 8) return;
    int e = t >> 3, h = t & 7;
    int si = src[e], di = dst[e];
    float x = el[(size_t)si * 8 + h] + er[(size_t)di * 8 + h];
    x = x < 0.f ? NEG_SLOPE * x : x;
    float a = __expf(x) / s[(size_t)di * 8 + h];
    const float4* f = (const float4*)(feat + (size_t)si * 128 + h * 16);
    float* o = outh + (size_t)di * 128 + h * 16;
#pragma unroll
    for (int q = 0; q < 4; q++) {
        float4 fv = f[q];
        atomicAdd(&o[q * 4 + 0], a * fv.x);
        atomicAdd(&o[q * 4 + 1], a * fv.y);
        atomicAdd(&o[q * 4 + 2], a * fv.z);
        atomicAdd(&o[q * 4 + 3], a * fv.w);
    }
}

extern "C" void kernel_launch(void* const* d_in, const int* in_sizes, int n_in,
                              void* d_out, int out_size, void* d_ws, size_t ws_size,
                              hipStream_t stream) {
    const float* features = (const float*)d_in[0];
    const int* pos_src = (const int*)d_in[1];
    const int* pos_dst = (const int*)d_in[2];
    const int* neg_src = (const int*)d_in[3];
    const int* neg_dst = (const int*)d_in[4];
    const float* W_pos  = (const float*)d_in[5];
    const float* al_pos = (const float*)d_in[6];
    const float* ar_pos = (const float*)d_in[7];
    const float* b_pos  = (const float*)d_in[8];
    const float* W_neg  = (const float*)d_in[9];
    const float* al_neg = (const float*)d_in[10];
    const float* ar_neg = (const float*)d_in[11];
    const float* b_neg  = (const float*)d_in[12];
    const float* W1 = (const float*)d_in[13];
    const float* b1 = (const float*)d_in[14];
    const float* W2 = (const float*)d_in[15];
    const float* b2 = (const float*)d_in[16];

    const int n  = in_sizes[0] / 128;   // 100000
    const int ne = in_sizes[1];         // 600000

    float* out  = (float*)d_out;
    float* hpos = out;
    float* hneg = out + (size_t)n * 128;
    float* hfin = out + (size_t)n * 256;

    float* ws = (float*)d_ws;
    float* feat_pos = ws;
    float* feat_neg = feat_pos + (size_t)n * 128;
    float* el_pos = feat_neg + (size_t)n * 128;
    float* er_pos = el_pos + (size_t)n * 8;
    float* el_neg = er_pos + (size_t)n * 8;
    float* er_neg = el_neg + (size_t)n * 8;
    float* s_pos  = er_neg + (size_t)n * 8;
    float* s_neg  = s_pos + (size_t)n * 8;
    float* tmid   = feat_pos;  // reuse: feat_pos dead after edge_acc(pos)

    const int gb = (n + 127) / 128;

    init_kernel<<<(n * 128 + 255) / 256, 256, 0, stream>>>(hpos, hneg, b_pos, b_neg, s_pos, s_neg, n);

    sgemm_kernel<128, 128, false, false><<<gb, 256, 0, stream>>>(features, nullptr, W_pos, nullptr, feat_pos, n);
    sgemm_kernel<128, 128, false, false><<<gb, 256, 0, stream>>>(features, nullptr, W_neg, nullptr, feat_neg, n);

    eler_kernel<<<(n * 8 + 255) / 256, 256, 0, stream>>>(feat_pos, al_pos, ar_pos, el_pos, er_pos, n);
    eler_kernel<<<(n * 8 + 255) / 256, 256, 0, stream>>>(feat_neg, al_neg, ar_neg, el_neg, er_neg, n);

    edge_s_kernel<<<(ne + 255) / 256, 256, 0, stream>>>(pos_src, pos_dst, el_pos, er_pos, s_pos, ne);
    edge_s_kernel<<<(ne + 255) / 256, 256, 0, stream>>>(neg_src, neg_dst, el_neg, er_neg, s_neg, ne);

    edge_acc_kernel<<<(ne * 8 + 255) / 256, 256, 0, stream>>>(pos_src, pos_dst, el_pos, er_pos, s_pos, feat_pos, hpos, ne);
    edge_acc_kernel<<<(ne * 8 + 255) / 256, 256, 0, stream>>>(neg_src, neg_dst, el_neg, er_neg, s_neg, feat_neg, hneg, ne);

    sgemm_kernel<256, 128, true, true><<<gb, 256, 0, stream>>>(hpos, hneg, W1, b1, tmid, n);
    sgemm_kernel<128, 64, false, false><<<gb, 128, 0, stream>>>(tmid, nullptr, W2, b2, hfin, n);
}

// Round 2
// 729.298 us; speedup vs baseline: 13.1262x; 13.1262x over previous
//
#include <hip/hip_runtime.h>

#define NEG_SLOPE 0.2f

// ---------------- SGEMM (unchanged from round 1) ----------------
template<int KDIM, int BN, bool CONCAT, bool RELU>
__global__ __launch_bounds__(BN * 2)
void sgemm_kernel(const float* __restrict__ X, const float* __restrict__ X2,
                  const float* __restrict__ W, const float* __restrict__ bias,
                  float* __restrict__ out, int n_rows) {
    constexpr int BM = 128, BK = 8;
    constexpr int NT = BN * 2;
    __shared__ float Xs[BK][BM];
    __shared__ float Ws[BK][BN];
    const int tid = threadIdx.x;
    const int tx = tid % (BN / 8);
    const int ty = tid / (BN / 8);
    const int row0 = blockIdx.x * BM;

    float acc[8][8];
#pragma unroll
    for (int i = 0; i < 8; i++)
#pragma unroll
        for (int j = 0; j < 8; j++) acc[i][j] = 0.f;

    for (int kb = 0; kb < KDIM / BK; ++kb) {
#pragma unroll
        for (int u = 0; u < (BM * BK) / (NT * 4); ++u) {
            int f = (tid + u * NT) * 4;
            int r = f >> 3;
            int c = f & 7;
            int gr = row0 + r;
            if (gr >= n_rows) gr = n_rows - 1;
            int k = kb * BK + c;
            const float* src;
            if (CONCAT) src = (k < 128) ? (X + (size_t)gr * 128 + k)
                                        : (X2 + (size_t)gr * 128 + (k - 128));
            else        src = X + (size_t)gr * KDIM + k;
            float4 v = *(const float4*)src;
            Xs[c + 0][r] = v.x; Xs[c + 1][r] = v.y;
            Xs[c + 2][r] = v.z; Xs[c + 3][r] = v.w;
        }
        {
            int f = tid * 4;
            int k = f / BN;
            int col = f % BN;
            float4 v = *(const float4*)(W + (size_t)(kb * BK + k) * BN + col);
            *(float4*)&Ws[k][col] = v;
        }
        __syncthreads();
#pragma unroll
        for (int kk = 0; kk < BK; ++kk) {
            float x[8], w[8];
            *(float4*)&x[0] = *(const float4*)&Xs[kk][ty * 8];
            *(float4*)&x[4] = *(const float4*)&Xs[kk][ty * 8 + 4];
            *(float4*)&w[0] = *(const float4*)&Ws[kk][tx * 8];
            *(float4*)&w[4] = *(const float4*)&Ws[kk][tx * 8 + 4];
#pragma unroll
            for (int i = 0; i < 8; i++)
#pragma unroll
                for (int j = 0; j < 8; j++) acc[i][j] = fmaf(x[i], w[j], acc[i][j]);
        }
        __syncthreads();
    }
#pragma unroll
    for (int i = 0; i < 8; i++) {
        int r = row0 + ty * 8 + i;
        if (r < n_rows) {
#pragma unroll
            for (int j0 = 0; j0 < 8; j0 += 4) {
                float vv[4];
#pragma unroll
                for (int j = 0; j < 4; j++) {
                    float t = acc[i][j0 + j];
                    if (bias) t += bias[tx * 8 + j0 + j];
                    if (RELU) t = t > 0.f ? t : 0.f;
                    vv[j] = t;
                }
                float4 v; v.x = vv[0]; v.y = vv[1]; v.z = vv[2]; v.w = vv[3];
                *(float4*)(out + (size_t)r * BN + tx * 8 + j0) = v;
            }
        }
    }
}

// el[n,h] = dot(feat[n,h,:], al[h,:]);  er likewise.
__global__ void eler_kernel(const float* __restrict__ feat, const float* __restrict__ al,
                            const float* __restrict__ ar, float* __restrict__ el,
                            float* __restrict__ er, int n) {
    int idx = blockIdx.x * blockDim.x + threadIdx.x;
    if (idx >= n * 8) return;
    int h = idx & 7;
    const float4* f = (const float4*)(feat + (size_t)idx * 16);
    const float4* a = (const float4*)(al + h * 16);
    const float4* b = (const float4*)(ar + h * 16);
    float sl = 0.f, sr = 0.f;
#pragma unroll
    for (int q = 0; q < 4; q++) {
        float4 fv = f[q], av = a[q], bv = b[q];
        sl += fv.x * av.x + fv.y * av.y + fv.z * av.z + fv.w * av.w;
        sr += fv.x * bv.x + fv.y * bv.y + fv.z * bv.z + fv.w * bv.w;
    }
    el[idx] = sl; er[idx] = sr;
}

// ---------------- CSR build: histogram -> scan -> scatter ----------------
__global__ void count_kernel(const int* __restrict__ dst, int* __restrict__ cnt, int ne) {
    int e = blockIdx.x * blockDim.x + threadIdx.x;
    if (e < ne) atomicAdd(&cnt[dst[e]], 1);
}

// In-place exclusive scan of each 256-block of cnt; block totals to bsum.
__global__ __launch_bounds__(256)
void scan1_kernel(int* __restrict__ cnt, int* __restrict__ bsum, int n) {
    __shared__ int sm[256];
    int i = blockIdx.x * 256 + threadIdx.x;
    int v = (i < n) ? cnt[i] : 0;
    sm[threadIdx.x] = v;
    __syncthreads();
    for (int off = 1; off < 256; off <<= 1) {
        int t = (threadIdx.x >= off) ? sm[threadIdx.x - off] : 0;
        __syncthreads();
        sm[threadIdx.x] += t;
        __syncthreads();
    }
    if (i < n) cnt[i] = sm[threadIdx.x] - v;          // exclusive within block
    if (threadIdx.x == 255) bsum[blockIdx.x] = sm[255];
}

// Single-block exclusive scan of block sums (nb <= 512).
__global__ __launch_bounds__(512)
void scan2_kernel(int* __restrict__ bsum, int nb) {
    __shared__ int sm[512];
    int v = (threadIdx.x < nb) ? bsum[threadIdx.x] : 0;
    sm[threadIdx.x] = v;
    __syncthreads();
    for (int off = 1; off < 512; off <<= 1) {
        int t = (threadIdx.x >= off) ? sm[threadIdx.x - off] : 0;
        __syncthreads();
        sm[threadIdx.x] += t;
        __syncthreads();
    }
    if (threadIdx.x < nb) bsum[threadIdx.x] = sm[threadIdx.x] - v;
}

// offs[i] = cnt[i] + bsum[i/256]; cnt becomes the scatter cursor (same value).
__global__ void scan3_kernel(int* __restrict__ cnt, const int* __restrict__ bsum,
                             int* __restrict__ offs, int n, int ne) {
    int i = blockIdx.x * blockDim.x + threadIdx.x;
    if (i < n) {
        int v = cnt[i] + bsum[i >> 8];
        offs[i] = v;
        cnt[i] = v;
    }
    if (i == 0) offs[n] = ne;
}

__global__ void scatter_kernel(const int* __restrict__ src, const int* __restrict__ dst,
                               int* __restrict__ cur, int* __restrict__ ssrc, int ne) {
    int e = blockIdx.x * blockDim.x + threadIdx.x;
    if (e >= ne) return;
    int p = atomicAdd(&cur[dst[e]], 1);
    ssrc[p] = src[e];
}

// ---------------- GAT gather: one wave per dst node, atomic-free ----------------
// Lane l owns output cols 2l,2l+1 (head = l/8). Online softmax denom (no shift;
// logits bounded, validated round 1). Bias folded in. Empty segment -> bias.
__global__ __launch_bounds__(256)
void gat_gather_kernel(const int* __restrict__ offs, const int* __restrict__ ssrc,
                       const float* __restrict__ el, const float* __restrict__ er,
                       const float* __restrict__ feat, const float* __restrict__ bias,
                       float* __restrict__ out, int n) {
    int node = (blockIdx.x * 256 + threadIdx.x) >> 6;
    int lane = threadIdx.x & 63;
    if (node >= n) return;
    int h = lane >> 3;
    float erh = er[(size_t)node * 8 + h];
    int beg = offs[node], end = offs[node + 1];
    float acc0 = 0.f, acc1 = 0.f, denom = 0.f;
    for (int p = beg; p < end; ++p) {
        int s = ssrc[p];
        float x = el[(size_t)s * 8 + h] + erh;
        x = x < 0.f ? NEG_SLOPE * x : x;
        float w = __expf(x);
        denom += w;
        float2 f = *(const float2*)(feat + (size_t)s * 128 + lane * 2);
        acc0 = fmaf(w, f.x, acc0);
        acc1 = fmaf(w, f.y, acc1);
    }
    float inv = denom > 0.f ? 1.f / denom : 0.f;
    float2 o;
    o.x = fmaf(acc0, inv, bias[lane * 2]);
    o.y = fmaf(acc1, inv, bias[lane * 2 + 1]);
    *(float2*)(out + (size_t)node * 128 + lane * 2) = o;
}

extern "C" void kernel_launch(void* const* d_in, const int* in_sizes, int n_in,
                              void* d_out, int out_size, void* d_ws, size_t ws_size,
                              hipStream_t stream) {
    const float* features = (const float*)d_in[0];
    const int* pos_src = (const int*)d_in[1];
    const int* pos_dst = (const int*)d_in[2];
    const int* neg_src = (const int*)d_in[3];
    const int* neg_dst = (const int*)d_in[4];
    const float* W_pos  = (const float*)d_in[5];
    const float* al_pos = (const float*)d_in[6];
    const float* ar_pos = (const float*)d_in[7];
    const float* b_pos  = (const float*)d_in[8];
    const float* W_neg  = (const float*)d_in[9];
    const float* al_neg = (const float*)d_in[10];
    const float* ar_neg = (const float*)d_in[11];
    const float* b_neg  = (const float*)d_in[12];
    const float* W1 = (const float*)d_in[13];
    const float* b1 = (const float*)d_in[14];
    const float* W2 = (const float*)d_in[15];
    const float* b2 = (const float*)d_in[16];

    const int n  = in_sizes[0] / 128;   // 100000
    const int ne = in_sizes[1];         // 600000
    const int nb = (n + 255) / 256;     // scan blocks (391)

    float* out  = (float*)d_out;
    float* hpos = out;
    float* hneg = out + (size_t)n * 128;
    float* hfin = out + (size_t)n * 256;

    float* ws = (float*)d_ws;
    float* feat_pos = ws;
    float* feat_neg = feat_pos + (size_t)n * 128;
    float* el_pos = feat_neg + (size_t)n * 128;
    float* er_pos = el_pos + (size_t)n * 8;
    float* el_neg = er_pos + (size_t)n * 8;
    float* er_neg = el_neg + (size_t)n * 8;
    int* cnt_pos  = (int*)(er_neg + (size_t)n * 8);  // n (hist -> part -> cursor)
    int* cnt_neg  = cnt_pos + n;                     // n
    int* offs_pos = cnt_neg + n;                     // n+1
    int* offs_neg = offs_pos + (n + 1);              // n+1
    int* bsum_pos = offs_neg + (n + 1);              // 512
    int* bsum_neg = bsum_pos + 512;                  // 512
    int* ssrc_pos = bsum_neg + 512;                  // ne
    int* ssrc_neg = ssrc_pos + ne;                   // ne
    float* tmid   = feat_pos;  // reuse: feat_pos dead after gat_gather(pos)

    const int gb = (n + 127) / 128;
    const int ge = (ne + 255) / 256;

    // CSR build (both edge sets)
    hipMemsetAsync(cnt_pos, 0, sizeof(int) * 2 * (size_t)n, stream);
    count_kernel<<<ge, 256, 0, stream>>>(pos_dst, cnt_pos, ne);
    count_kernel<<<ge, 256, 0, stream>>>(neg_dst, cnt_neg, ne);
    scan1_kernel<<<nb, 256, 0, stream>>>(cnt_pos, bsum_pos, n);
    scan1_kernel<<<nb, 256, 0, stream>>>(cnt_neg, bsum_neg, n);
    scan2_kernel<<<1, 512, 0, stream>>>(bsum_pos, nb);
    scan2_kernel<<<1, 512, 0, stream>>>(bsum_neg, nb);
    scan3_kernel<<<nb, 256, 0, stream>>>(cnt_pos, bsum_pos, offs_pos, n, ne);
    scan3_kernel<<<nb, 256, 0, stream>>>(cnt_neg, bsum_neg, offs_neg, n, ne);
    scatter_kernel<<<ge, 256, 0, stream>>>(pos_src, pos_dst, cnt_pos, ssrc_pos, ne);
    scatter_kernel<<<ge, 256, 0, stream>>>(neg_src, neg_dst, cnt_neg, ssrc_neg, ne);

    // Feature transforms
    sgemm_kernel<128, 128, false, false><<<gb, 256, 0, stream>>>(features, nullptr, W_pos, nullptr, feat_pos, n);
    sgemm_kernel<128, 128, false, false><<<gb, 256, 0, stream>>>(features, nullptr, W_neg, nullptr, feat_neg, n);

    eler_kernel<<<(n * 8 + 255) / 256, 256, 0, stream>>>(feat_pos, al_pos, ar_pos, el_pos, er_pos, n);
    eler_kernel<<<(n * 8 + 255) / 256, 256, 0, stream>>>(feat_neg, al_neg, ar_neg, el_neg, er_neg, n);

    // Atomic-free GAT aggregation (fused softmax denom + weighted sum + bias)
    gat_gather_kernel<<<(n + 3) / 4, 256, 0, stream>>>(offs_pos, ssrc_pos, el_pos, er_pos, feat_pos, b_pos, hpos, n);
    gat_gather_kernel<<<(n + 3) / 4, 256, 0, stream>>>(offs_neg, ssrc_neg, el_neg, er_neg, feat_neg, b_neg, hneg, n);

    // MLP
    sgemm_kernel<256, 128, true, true><<<gb, 256, 0, stream>>>(hpos, hneg, W1, b1, tmid, n);
    sgemm_kernel<128, 64, false, false><<<gb, 128, 0, stream>>>(tmid, nullptr, W2, b2, hfin, n);
}

// Round 3
// 578.795 us; speedup vs baseline: 16.5394x; 1.2600x over previous
//
#include <hip/hip_runtime.h>

#define NEG_SLOPE 0.2f

typedef __attribute__((ext_vector_type(8))) short short8;
typedef __attribute__((ext_vector_type(4))) float floatx4;

__device__ __forceinline__ unsigned short f2bf(float f) {
    union { float f; unsigned u; } v; v.f = f;
    unsigned r = v.u + 0x7FFF + ((v.u >> 16) & 1);   // RN-even
    return (unsigned short)(r >> 16);
}

// ---------------- converts ----------------
__global__ void convert_x_kernel(const float* __restrict__ x, unsigned short* __restrict__ xb, int total8) {
    int i = blockIdx.x * blockDim.x + threadIdx.x;
    if (i >= total8) return;
    const float4* p = (const float4*)(x + (size_t)i * 8);
    float4 a = p[0], b = p[1];
    unsigned short o[8];
    o[0] = f2bf(a.x); o[1] = f2bf(a.y); o[2] = f2bf(a.z); o[3] = f2bf(a.w);
    o[4] = f2bf(b.x); o[5] = f2bf(b.y); o[6] = f2bf(b.z); o[7] = f2bf(b.w);
    *(float4*)(xb + (size_t)i * 8) = *(float4*)o;
}

// Transpose + convert all weights: Wcat[256][128] (pos|neg), W1t[128][256], W2t[64][128]
__global__ void convert_w_kernel(const float* __restrict__ Wp, const float* __restrict__ Wn,
                                 const float* __restrict__ W1, const float* __restrict__ W2,
                                 unsigned short* __restrict__ Wcat, unsigned short* __restrict__ W1t,
                                 unsigned short* __restrict__ W2t) {
    int i = blockIdx.x * blockDim.x + threadIdx.x;
    if (i < 256 * 128) {
        int nr = i >> 7, k = i & 127;
        float v = (nr < 128) ? Wp[k * 128 + nr] : Wn[k * 128 + (nr - 128)];
        Wcat[i] = f2bf(v);
    } else if (i < 256 * 128 + 128 * 256) {
        int j = i - 256 * 128;
        int nr = j >> 8, k = j & 255;
        W1t[j] = f2bf(W1[k * 128 + nr]);
    } else if (i < 256 * 128 + 128 * 256 + 64 * 128) {
        int j = i - 256 * 128 - 128 * 256;
        int nr = j >> 7, k = j & 127;
        W2t[j] = f2bf(W2[k * 64 + nr]);
    }
}

// ---------------- bf16 MFMA GEMM ----------------
// out[y*M*BN + m*BN + nloc] = op(A[m, :K] @ Wt[y*BN + nloc, :K]^T + bias)
// BM=128, 4 waves in 2x2 grid, wave tile 64 x BN/2, 16x16x32 MFMA, fp32 acc.
template<int KDIM, int BN, bool RELU, bool OUT_BF16>
__global__ __launch_bounds__(256)
void mfma_gemm_kernel(const unsigned short* __restrict__ A, const unsigned short* __restrict__ Wt,
                      const float* __restrict__ bias, void* __restrict__ outv, int n_rows) {
    constexpr int BM = 128, BK = 64;
    constexpr int LDA = BK + 8;          // 144B row stride -> 2-way bank alias only
    constexpr int NT = BN / 32;          // n-frags per wave
    __shared__ unsigned short As[BM * LDA];
    __shared__ unsigned short Bs[BN * LDA];
    const int tid = threadIdx.x;
    const int lane = tid & 63;
    const int wave = tid >> 6;
    const int wy = wave >> 1, wx = wave & 1;
    const int row0 = blockIdx.x * BM;
    const int n0 = blockIdx.y * BN;
    const int lrow = lane & 15;
    const int lk = (lane >> 4) * 8;

    floatx4 acc[4][NT];
#pragma unroll
    for (int mt = 0; mt < 4; mt++)
#pragma unroll
        for (int nt = 0; nt < NT; nt++) acc[mt][nt] = (floatx4){0.f, 0.f, 0.f, 0.f};

    for (int kb = 0; kb < KDIM / BK; ++kb) {
#pragma unroll
        for (int u = 0; u < 4; ++u) {            // A: 128x64 bf16
            int idx = tid + u * 256;
            int r = idx >> 3, c8 = idx & 7;
            int gr = row0 + r; if (gr >= n_rows) gr = n_rows - 1;
            float4 v = *(const float4*)(A + (size_t)gr * KDIM + kb * BK + c8 * 8);
            *(float4*)&As[r * LDA + c8 * 8] = v;
        }
#pragma unroll
        for (int u = 0; u < BN / 32; ++u) {      // B: BNx64 bf16
            int idx = tid + u * 256;
            int r = idx >> 3, c8 = idx & 7;
            float4 v = *(const float4*)(Wt + (size_t)(n0 + r) * KDIM + kb * BK + c8 * 8);
            *(float4*)&Bs[r * LDA + c8 * 8] = v;
        }
        __syncthreads();
#pragma unroll
        for (int ks = 0; ks < 2; ++ks) {
            short8 af[4], bf[NT];
#pragma unroll
            for (int mt = 0; mt < 4; ++mt)
                af[mt] = *(const short8*)&As[(wy * 64 + mt * 16 + lrow) * LDA + ks * 32 + lk];
#pragma unroll
            for (int nt = 0; nt < NT; ++nt)
                bf[nt] = *(const short8*)&Bs[(wx * (BN / 2) + nt * 16 + lrow) * LDA + ks * 32 + lk];
#pragma unroll
            for (int mt = 0; mt < 4; ++mt)
#pragma unroll
                for (int nt = 0; nt < NT; ++nt)
                    acc[mt][nt] = __builtin_amdgcn_mfma_f32_16x16x32_bf16(af[mt], bf[nt], acc[mt][nt], 0, 0, 0);
        }
        __syncthreads();
    }
    // epilogue: D[row=(lane>>4)*4+r][col=lane&15]
    const size_t obase = (size_t)blockIdx.y * n_rows * BN;
#pragma unroll
    for (int mt = 0; mt < 4; ++mt) {
#pragma unroll
        for (int r = 0; r < 4; ++r) {
            int grow = row0 + wy * 64 + mt * 16 + (lane >> 4) * 4 + r;
            if (grow >= n_rows) continue;
#pragma unroll
            for (int nt = 0; nt < NT; ++nt) {
                int cloc = wx * (BN / 2) + nt * 16 + (lane & 15);
                float v = acc[mt][nt][r];
                if (bias) v += bias[cloc];
                if (RELU) v = fmaxf(v, 0.f);
                if (OUT_BF16) ((unsigned short*)outv)[obase + (size_t)grow * BN + cloc] = f2bf(v);
                else          ((float*)outv)[obase + (size_t)grow * BN + cloc] = v;
            }
        }
    }
}

// el[n,h] = dot(feat[n,h,:], al[h,:]);  er likewise.
__global__ void eler_kernel(const float* __restrict__ feat, const float* __restrict__ al,
                            const float* __restrict__ ar, float* __restrict__ el,
                            float* __restrict__ er, int n) {
    int idx = blockIdx.x * blockDim.x + threadIdx.x;
    if (idx >= n * 8) return;
    int h = idx & 7;
    const float4* f = (const float4*)(feat + (size_t)idx * 16);
    const float4* a = (const float4*)(al + h * 16);
    const float4* b = (const float4*)(ar + h * 16);
    float sl = 0.f, sr = 0.f;
#pragma unroll
    for (int q = 0; q < 4; q++) {
        float4 fv = f[q], av = a[q], bv = b[q];
        sl += fv.x * av.x + fv.y * av.y + fv.z * av.z + fv.w * av.w;
        sr += fv.x * bv.x + fv.y * bv.y + fv.z * bv.z + fv.w * bv.w;
    }
    el[idx] = sl; er[idx] = sr;
}

// ---------------- CSR build ----------------
__global__ void count_kernel(const int* __restrict__ dst, int* __restrict__ cnt, int ne) {
    int e = blockIdx.x * blockDim.x + threadIdx.x;
    if (e < ne) atomicAdd(&cnt[dst[e]], 1);
}

__global__ __launch_bounds__(256)
void scan1_kernel(int* __restrict__ cnt, int* __restrict__ bsum, int n) {
    __shared__ int sm[256];
    int i = blockIdx.x * 256 + threadIdx.x;
    int v = (i < n) ? cnt[i] : 0;
    sm[threadIdx.x] = v;
    __syncthreads();
    for (int off = 1; off < 256; off <<= 1) {
        int t = (threadIdx.x >= off) ? sm[threadIdx.x - off] : 0;
        __syncthreads();
        sm[threadIdx.x] += t;
        __syncthreads();
    }
    if (i < n) cnt[i] = sm[threadIdx.x] - v;
    if (threadIdx.x == 255) bsum[blockIdx.x] = sm[255];
}

__global__ __launch_bounds__(512)
void scan2_kernel(int* __restrict__ bsum, int nb) {
    __shared__ int sm[512];
    int v = (threadIdx.x < nb) ? bsum[threadIdx.x] : 0;
    sm[threadIdx.x] = v;
    __syncthreads();
    for (int off = 1; off < 512; off <<= 1) {
        int t = (threadIdx.x >= off) ? sm[threadIdx.x - off] : 0;
        __syncthreads();
        sm[threadIdx.x] += t;
        __syncthreads();
    }
    if (threadIdx.x < nb) bsum[threadIdx.x] = sm[threadIdx.x] - v;
}

__global__ void scan3_kernel(int* __restrict__ cnt, const int* __restrict__ bsum,
                             int* __restrict__ offs, int n, int ne) {
    int i = blockIdx.x * blockDim.x + threadIdx.x;
    if (i < n) {
        int v = cnt[i] + bsum[i >> 8];
        offs[i] = v;
        cnt[i] = v;
    }
    if (i == 0) offs[n] = ne;
}

__global__ void scatter_kernel(const int* __restrict__ src, const int* __restrict__ dst,
                               int* __restrict__ cur, int* __restrict__ ssrc, int ne) {
    int e = blockIdx.x * blockDim.x + threadIdx.x;
    if (e >= ne) return;
    int p = atomicAdd(&cur[dst[e]], 1);
    ssrc[p] = src[e];
}

// ---------------- GAT gather: one wave per dst node ----------------
// Dual store: fp32 h to d_out, bf16 copy into hcat[n][256] at column coloff.
__global__ __launch_bounds__(256)
void gat_gather_kernel(const int* __restrict__ offs, const int* __restrict__ ssrc,
                       const float* __restrict__ el, const float* __restrict__ er,
                       const float* __restrict__ feat, const float* __restrict__ bias,
                       float* __restrict__ out, unsigned short* __restrict__ hcatb,
                       int coloff, int n) {
    int node = (blockIdx.x * 256 + threadIdx.x) >> 6;
    int lane = threadIdx.x & 63;
    if (node >= n) return;
    int h = lane >> 3;
    float erh = er[(size_t)node * 8 + h];
    int beg = offs[node], end = offs[node + 1];
    float acc0 = 0.f, acc1 = 0.f, denom = 0.f;
    for (int p = beg; p < end; ++p) {
        int s = ssrc[p];
        float x = el[(size_t)s * 8 + h] + erh;
        x = x < 0.f ? NEG_SLOPE * x : x;
        float w = __expf(x);
        denom += w;
        float2 f = *(const float2*)(feat + (size_t)s * 128 + lane * 2);
        acc0 = fmaf(w, f.x, acc0);
        acc1 = fmaf(w, f.y, acc1);
    }
    float inv = denom > 0.f ? 1.f / denom : 0.f;
    float2 o;
    o.x = fmaf(acc0, inv, bias[lane * 2]);
    o.y = fmaf(acc1, inv, bias[lane * 2 + 1]);
    *(float2*)(out + (size_t)node * 128 + lane * 2) = o;
    ushort2 hb; hb.x = f2bf(o.x); hb.y = f2bf(o.y);
    *(ushort2*)(hcatb + (size_t)node * 256 + coloff + lane * 2) = hb;
}

extern "C" void kernel_launch(void* const* d_in, const int* in_sizes, int n_in,
                              void* d_out, int out_size, void* d_ws, size_t ws_size,
                              hipStream_t stream) {
    const float* features = (const float*)d_in[0];
    const int* pos_src = (const int*)d_in[1];
    const int* pos_dst = (const int*)d_in[2];
    const int* neg_src = (const int*)d_in[3];
    const int* neg_dst = (const int*)d_in[4];
    const float* W_pos  = (const float*)d_in[5];
    const float* al_pos = (const float*)d_in[6];
    const float* ar_pos = (const float*)d_in[7];
    const float* b_pos  = (const float*)d_in[8];
    const float* W_neg  = (const float*)d_in[9];
    const float* al_neg = (const float*)d_in[10];
    const float* ar_neg = (const float*)d_in[11];
    const float* b_neg  = (const float*)d_in[12];
    const float* W1 = (const float*)d_in[13];
    const float* b1 = (const float*)d_in[14];
    const float* W2 = (const float*)d_in[15];
    const float* b2 = (const float*)d_in[16];

    const int n  = in_sizes[0] / 128;   // 100000
    const int ne = in_sizes[1];         // 600000
    const int nb = (n + 255) / 256;

    float* out  = (float*)d_out;
    float* hpos = out;
    float* hneg = out + (size_t)n * 128;
    float* hfin = out + (size_t)n * 256;

    float* ws = (float*)d_ws;
    float* feat_pos = ws;                             // n*128 (feat_neg adjacent!)
    float* feat_neg = feat_pos + (size_t)n * 128;     // n*128
    float* el_pos = feat_neg + (size_t)n * 128;
    float* er_pos = el_pos + (size_t)n * 8;
    float* el_neg = er_pos + (size_t)n * 8;
    float* er_neg = el_neg + (size_t)n * 8;
    unsigned short* hcatb = (unsigned short*)(er_neg + (size_t)n * 8);   // n*256 bf16
    unsigned short* XbR   = hcatb + (size_t)n * 256;  // n*128 bf16: Xb, later reused as mid
    unsigned short* Wcat  = XbR + (size_t)n * 128;    // 256*128
    unsigned short* W1t   = Wcat + 256 * 128;         // 128*256
    unsigned short* W2t   = W1t + 128 * 256;          // 64*128
    int* cnt_pos  = (int*)(W2t + 64 * 128);
    int* cnt_neg  = cnt_pos + n;
    int* offs_pos = cnt_neg + n;
    int* offs_neg = offs_pos + (n + 1);
    int* bsum_pos = offs_neg + (n + 1);
    int* bsum_neg = bsum_pos + 512;
    int* ssrc_pos = bsum_neg + 512;
    int* ssrc_neg = ssrc_pos + ne;
    unsigned short* Xb  = XbR;
    unsigned short* mid = XbR;   // Xb dead after feat GEMM; mid written by MLP1

    const int gm = (n + 127) / 128;       // 782
    const int ge = (ne + 255) / 256;

    // converts
    convert_x_kernel<<<(n * 16 + 255) / 256, 256, 0, stream>>>(features, Xb, n * 16);
    convert_w_kernel<<<(73728 + 255) / 256, 256, 0, stream>>>(W_pos, W_neg, W1, W2, Wcat, W1t, W2t);

    // CSR build
    hipMemsetAsync(cnt_pos, 0, sizeof(int) * 2 * (size_t)n, stream);
    count_kernel<<<ge, 256, 0, stream>>>(pos_dst, cnt_pos, ne);
    count_kernel<<<ge, 256, 0, stream>>>(neg_dst, cnt_neg, ne);
    scan1_kernel<<<nb, 256, 0, stream>>>(cnt_pos, bsum_pos, n);
    scan1_kernel<<<nb, 256, 0, stream>>>(cnt_neg, bsum_neg, n);
    scan2_kernel<<<1, 512, 0, stream>>>(bsum_pos, nb);
    scan2_kernel<<<1, 512, 0, stream>>>(bsum_neg, nb);
    scan3_kernel<<<nb, 256, 0, stream>>>(cnt_pos, bsum_pos, offs_pos, n, ne);
    scan3_kernel<<<nb, 256, 0, stream>>>(cnt_neg, bsum_neg, offs_neg, n, ne);
    scatter_kernel<<<ge, 256, 0, stream>>>(pos_src, pos_dst, cnt_pos, ssrc_pos, ne);
    scatter_kernel<<<ge, 256, 0, stream>>>(neg_src, neg_dst, cnt_neg, ssrc_neg, ne);

    // fused feat GEMM: y=0 -> feat_pos (Wcat rows 0-127), y=1 -> feat_neg
    mfma_gemm_kernel<128, 128, false, false><<<dim3(gm, 2), 256, 0, stream>>>(Xb, Wcat, nullptr, feat_pos, n);

    eler_kernel<<<(n * 8 + 255) / 256, 256, 0, stream>>>(feat_pos, al_pos, ar_pos, el_pos, er_pos, n);
    eler_kernel<<<(n * 8 + 255) / 256, 256, 0, stream>>>(feat_neg, al_neg, ar_neg, el_neg, er_neg, n);

    gat_gather_kernel<<<(n + 3) / 4, 256, 0, stream>>>(offs_pos, ssrc_pos, el_pos, er_pos, feat_pos, b_pos, hpos, hcatb, 0, n);
    gat_gather_kernel<<<(n + 3) / 4, 256, 0, stream>>>(offs_neg, ssrc_neg, el_neg, er_neg, feat_neg, b_neg, hneg, hcatb, 128, n);

    // MLP (bf16 MFMA)
    mfma_gemm_kernel<256, 128, true, true><<<dim3(gm, 1), 256, 0, stream>>>(hcatb, W1t, b1, mid, n);
    mfma_gemm_kernel<128, 64, false, false><<<dim3(gm, 1), 256, 0, stream>>>(mid, W2t, b2, hfin, n);
}

// Round 4
// 512.160 us; speedup vs baseline: 18.6912x; 1.1301x over previous
//
#include <hip/hip_runtime.h>

#define NEG_SLOPE 0.2f

typedef __attribute__((ext_vector_type(8))) short short8;
typedef __attribute__((ext_vector_type(4))) float floatx4;

__device__ __forceinline__ unsigned short f2bf(float f) {
    union { float f; unsigned u; } v; v.f = f;
    unsigned r = v.u + 0x7FFF + ((v.u >> 16) & 1);   // RN-even
    return (unsigned short)(r >> 16);
}
__device__ __forceinline__ float bf2f(unsigned short u) {
    return __uint_as_float(((unsigned)u) << 16);
}

// ---------------- weight transpose+convert ----------------
// Wcat[256][128] (pos|neg), W1t[128][256], W2t[64][128], all bf16 row=outcol.
__global__ void convert_w_kernel(const float* __restrict__ Wp, const float* __restrict__ Wn,
                                 const float* __restrict__ W1, const float* __restrict__ W2,
                                 unsigned short* __restrict__ Wcat, unsigned short* __restrict__ W1t,
                                 unsigned short* __restrict__ W2t) {
    int i = blockIdx.x * blockDim.x + threadIdx.x;
    if (i < 256 * 128) {
        int nr = i >> 7, k = i & 127;
        float v = (nr < 128) ? Wp[k * 128 + nr] : Wn[k * 128 + (nr - 128)];
        Wcat[i] = f2bf(v);
    } else if (i < 256 * 128 + 128 * 256) {
        int j = i - 256 * 128;
        int nr = j >> 8, k = j & 255;
        W1t[j] = f2bf(W1[k * 128 + nr]);
    } else if (i < 256 * 128 + 128 * 256 + 64 * 128) {
        int j = i - 256 * 128 - 128 * 256;
        int nr = j >> 7, k = j & 127;
        W2t[j] = f2bf(W2[k * 64 + nr]);
    }
}

// ---------------- bf16 MFMA GEMM ----------------
// out[y-block][m][nloc] = op(A[m,:K] @ Wt[n0+nloc,:K]^T + bias).
// BM=128, 4 waves 2x2, 16x16x32 bf16 MFMA, fp32 acc. IN_F32: A is fp32, convert in staging.
template<int KDIM, int BN, bool IN_F32, bool RELU, bool OUT_BF16>
__global__ __launch_bounds__(256)
void mfma_gemm_kernel(const void* __restrict__ Av, const unsigned short* __restrict__ Wt,
                      const float* __restrict__ bias, void* __restrict__ outv, int n_rows) {
    constexpr int BM = 128, BK = 64;
    constexpr int LDA = BK + 8;          // 144B row stride -> 2-way bank alias only
    constexpr int NT = BN / 32;
    __shared__ unsigned short As[BM * LDA];
    __shared__ unsigned short Bs[BN * LDA];
    const int tid = threadIdx.x;
    const int lane = tid & 63;
    const int wave = tid >> 6;
    const int wy = wave >> 1, wx = wave & 1;
    const int row0 = blockIdx.x * BM;
    const int n0 = blockIdx.y * BN;
    const int lrow = lane & 15;
    const int lk = (lane >> 4) * 8;

    floatx4 acc[4][NT];
#pragma unroll
    for (int mt = 0; mt < 4; mt++)
#pragma unroll
        for (int nt = 0; nt < NT; nt++) acc[mt][nt] = (floatx4){0.f, 0.f, 0.f, 0.f};

    for (int kb = 0; kb < KDIM / BK; ++kb) {
#pragma unroll
        for (int u = 0; u < 4; ++u) {            // A: 128x64
            int idx = tid + u * 256;
            int r = idx >> 3, c8 = idx & 7;
            int gr = row0 + r; if (gr >= n_rows) gr = n_rows - 1;
            if (IN_F32) {
                const float* Af = (const float*)Av + (size_t)gr * KDIM + kb * BK + c8 * 8;
                float4 va = ((const float4*)Af)[0], vb = ((const float4*)Af)[1];
                unsigned short o[8];
                o[0] = f2bf(va.x); o[1] = f2bf(va.y); o[2] = f2bf(va.z); o[3] = f2bf(va.w);
                o[4] = f2bf(vb.x); o[5] = f2bf(vb.y); o[6] = f2bf(vb.z); o[7] = f2bf(vb.w);
                *(float4*)&As[r * LDA + c8 * 8] = *(float4*)o;
            } else {
                const unsigned short* Ab = (const unsigned short*)Av;
                float4 v = *(const float4*)(Ab + (size_t)gr * KDIM + kb * BK + c8 * 8);
                *(float4*)&As[r * LDA + c8 * 8] = v;
            }
        }
#pragma unroll
        for (int u = 0; u < BN / 32; ++u) {      // B: BNx64 bf16
            int idx = tid + u * 256;
            int r = idx >> 3, c8 = idx & 7;
            float4 v = *(const float4*)(Wt + (size_t)(n0 + r) * KDIM + kb * BK + c8 * 8);
            *(float4*)&Bs[r * LDA + c8 * 8] = v;
        }
        __syncthreads();
#pragma unroll
        for (int ks = 0; ks < 2; ++ks) {
            short8 af[4], bf[NT];
#pragma unroll
            for (int mt = 0; mt < 4; ++mt)
                af[mt] = *(const short8*)&As[(wy * 64 + mt * 16 + lrow) * LDA + ks * 32 + lk];
#pragma unroll
            for (int nt = 0; nt < NT; ++nt)
                bf[nt] = *(const short8*)&Bs[(wx * (BN / 2) + nt * 16 + lrow) * LDA + ks * 32 + lk];
#pragma unroll
            for (int mt = 0; mt < 4; ++mt)
#pragma unroll
                for (int nt = 0; nt < NT; ++nt)
                    acc[mt][nt] = __builtin_amdgcn_mfma_f32_16x16x32_bf16(af[mt], bf[nt], acc[mt][nt], 0, 0, 0);
        }
        __syncthreads();
    }
    const size_t obase = (size_t)blockIdx.y * n_rows * BN;
#pragma unroll
    for (int mt = 0; mt < 4; ++mt) {
#pragma unroll
        for (int r = 0; r < 4; ++r) {
            int grow = row0 + wy * 64 + mt * 16 + (lane >> 4) * 4 + r;
            if (grow >= n_rows) continue;
#pragma unroll
            for (int nt = 0; nt < NT; ++nt) {
                int cloc = wx * (BN / 2) + nt * 16 + (lane & 15);
                float v = acc[mt][nt][r];
                if (bias) v += bias[cloc];
                if (RELU) v = fmaxf(v, 0.f);
                if (OUT_BF16) ((unsigned short*)outv)[obase + (size_t)grow * BN + cloc] = f2bf(v);
                else          ((float*)outv)[obase + (size_t)grow * BN + cloc] = v;
            }
        }
    }
}

// ---------------- eler (fused pos+neg, bf16 feat) ----------------
__global__ void eler_kernel(const unsigned short* __restrict__ featb,
                            const float* __restrict__ al_p, const float* __restrict__ ar_p,
                            const float* __restrict__ al_n, const float* __restrict__ ar_n,
                            float* __restrict__ el_p, float* __restrict__ er_p,
                            float* __restrict__ el_n, float* __restrict__ er_n, int n) {
    int idx = blockIdx.x * blockDim.x + threadIdx.x;   // over 2n*8
    if (idx >= 2 * n * 8) return;
    int h = idx & 7;
    bool neg = idx >= n * 8;
    const float* al = neg ? al_n : al_p;
    const float* ar = neg ? ar_n : ar_p;
    float* el = neg ? el_n : el_p;
    float* er = neg ? er_n : er_p;
    int local = neg ? idx - n * 8 : idx;
    const unsigned* fu = (const unsigned*)(featb + (size_t)idx * 16);
    float sl = 0.f, sr = 0.f;
#pragma unroll
    for (int q = 0; q < 8; ++q) {
        unsigned u = fu[q];
        float lo = __uint_as_float(u << 16);
        float hi = __uint_as_float(u & 0xFFFF0000u);
        sl += lo * al[h * 16 + q * 2] + hi * al[h * 16 + q * 2 + 1];
        sr += lo * ar[h * 16 + q * 2] + hi * ar[h * 16 + q * 2 + 1];
    }
    el[local] = sl; er[local] = sr;
}

// ---------------- CSR build (pos+neg fused; neg at cnt offset npad) ----------------
__global__ void count_kernel(const int* __restrict__ pos_dst, const int* __restrict__ neg_dst,
                             int* __restrict__ cnt, int ne, int npad) {
    int e = blockIdx.x * blockDim.x + threadIdx.x;
    if (e < ne) atomicAdd(&cnt[pos_dst[e]], 1);
    else if (e < 2 * ne) atomicAdd(&cnt[npad + neg_dst[e - ne]], 1);
}

__global__ __launch_bounds__(256)
void scan1_kernel(int* __restrict__ cnt, int* __restrict__ bsum) {
    __shared__ int sm[256];
    int i = blockIdx.x * 256 + threadIdx.x;
    int v = cnt[i];
    sm[threadIdx.x] = v;
    __syncthreads();
    for (int off = 1; off < 256; off <<= 1) {
        int t = (threadIdx.x >= off) ? sm[threadIdx.x - off] : 0;
        __syncthreads();
        sm[threadIdx.x] += t;
        __syncthreads();
    }
    cnt[i] = sm[threadIdx.x] - v;
    if (threadIdx.x == 255) bsum[blockIdx.x] = sm[255];
}

// grid.x=2 halves; each block scans its half of bsum independently (nb <= 512).
__global__ __launch_bounds__(512)
void scan2_kernel(int* __restrict__ bsum, int nb) {
    __shared__ int sm[512];
    int base = blockIdx.x * nb;
    int v = (threadIdx.x < nb) ? bsum[base + threadIdx.x] : 0;
    sm[threadIdx.x] = v;
    __syncthreads();
    for (int off = 1; off < 512; off <<= 1) {
        int t = (threadIdx.x >= off) ? sm[threadIdx.x - off] : 0;
        __syncthreads();
        sm[threadIdx.x] += t;
        __syncthreads();
    }
    if (threadIdx.x < nb) bsum[base + threadIdx.x] = sm[threadIdx.x] - v;
}

__global__ void scan3_kernel(int* __restrict__ cnt, const int* __restrict__ bsum,
                             int* __restrict__ offs_p, int* __restrict__ offs_n,
                             int n, int ne, int npad) {
    int i = blockIdx.x * blockDim.x + threadIdx.x;   // over 2*npad
    int v = cnt[i] + bsum[i >> 8];
    cnt[i] = v;
    if (i < n) offs_p[i] = v;
    else if (i >= npad && i - npad < n) offs_n[i - npad] = v;
    if (i == 0) { offs_p[n] = ne; offs_n[n] = ne; }
}

__global__ void scatter_kernel(const int* __restrict__ pos_src, const int* __restrict__ pos_dst,
                               const int* __restrict__ neg_src, const int* __restrict__ neg_dst,
                               int* __restrict__ cur, int* __restrict__ ssrc_p, int* __restrict__ ssrc_n,
                               int ne, int npad) {
    int e = blockIdx.x * blockDim.x + threadIdx.x;
    if (e < ne) {
        int p = atomicAdd(&cur[pos_dst[e]], 1);
        ssrc_p[p] = pos_src[e];
    } else if (e < 2 * ne) {
        int j = e - ne;
        int p = atomicAdd(&cur[npad + neg_dst[j]], 1);
        ssrc_n[p] = neg_src[j];
    }
}

// ---------------- GAT gather (pos+neg via grid.y, bf16 feat, latency-pipelined) ----------------
__global__ __launch_bounds__(256)
void gat_gather_kernel(const int* __restrict__ offs_p, const int* __restrict__ offs_n,
                       const int* __restrict__ ssrc_p, const int* __restrict__ ssrc_n,
                       const float* __restrict__ el_p, const float* __restrict__ er_p,
                       const float* __restrict__ el_n, const float* __restrict__ er_n,
                       const unsigned short* __restrict__ featb,   // [2n][128] bf16
                       const float* __restrict__ b_pos, const float* __restrict__ b_neg,
                       float* __restrict__ out, unsigned short* __restrict__ hcatb, int n) {
    int node = (blockIdx.x * 256 + threadIdx.x) >> 6;
    int lane = threadIdx.x & 63;
    if (node >= n) return;
    const int neg = blockIdx.y;
    const int* offs = neg ? offs_n : offs_p;
    const int* ssrc = neg ? ssrc_n : ssrc_p;
    const float* el = neg ? el_n : el_p;
    const float* er = neg ? er_n : er_p;
    const unsigned short* fb = featb + (size_t)(neg ? n : 0) * 128;
    const float* bias = neg ? b_neg : b_pos;
    float* o = out + (size_t)(neg ? n : 0) * 128;
    const int coloff = neg ? 128 : 0;

    const int h = lane >> 3;
    const float erh = er[(size_t)node * 8 + h];
    const int beg = offs[node], end = offs[node + 1];
    float acc0 = 0.f, acc1 = 0.f, denom = 0.f;

#define GSTEP(S)  do {                                                         \
        float x_ = el[(size_t)(S) * 8 + h] + erh;                              \
        x_ = x_ < 0.f ? NEG_SLOPE * x_ : x_;                                   \
        float w_ = __expf(x_);                                                 \
        denom += w_;                                                           \
        ushort2 f_ = *(const ushort2*)(fb + (size_t)(S) * 128 + lane * 2);     \
        acc0 = fmaf(w_, bf2f(f_.x), acc0);                                     \
        acc1 = fmaf(w_, bf2f(f_.y), acc1);                                     \
    } while (0)

    for (int p0 = beg; p0 < end; p0 += 64) {
        int cnt = end - p0; if (cnt > 64) cnt = 64;
        int sid = (lane < cnt) ? ssrc[p0 + lane] : 0;   // one coalesced load / 64 edges
        int j = 0;
        for (; j + 4 <= cnt; j += 4) {
            int s0 = __shfl(sid, j), s1 = __shfl(sid, j + 1);
            int s2 = __shfl(sid, j + 2), s3 = __shfl(sid, j + 3);
            GSTEP(s0); GSTEP(s1); GSTEP(s2); GSTEP(s3);
        }
        for (; j < cnt; ++j) {
            int s = __shfl(sid, j);
            GSTEP(s);
        }
    }
#undef GSTEP

    float inv = denom > 0.f ? 1.f / denom : 0.f;
    float2 ov;
    ov.x = fmaf(acc0, inv, bias[lane * 2]);
    ov.y = fmaf(acc1, inv, bias[lane * 2 + 1]);
    *(float2*)(o + (size_t)node * 128 + lane * 2) = ov;
    ushort2 hb; hb.x = f2bf(ov.x); hb.y = f2bf(ov.y);
    *(ushort2*)(hcatb + (size_t)node * 256 + coloff + lane * 2) = hb;
}

extern "C" void kernel_launch(void* const* d_in, const int* in_sizes, int n_in,
                              void* d_out, int out_size, void* d_ws, size_t ws_size,
                              hipStream_t stream) {
    const float* features = (const float*)d_in[0];
    const int* pos_src = (const int*)d_in[1];
    const int* pos_dst = (const int*)d_in[2];
    const int* neg_src = (const int*)d_in[3];
    const int* neg_dst = (const int*)d_in[4];
    const float* W_pos  = (const float*)d_in[5];
    const float* al_pos = (const float*)d_in[6];
    const float* ar_pos = (const float*)d_in[7];
    const float* b_pos  = (const float*)d_in[8];
    const float* W_neg  = (const float*)d_in[9];
    const float* al_neg = (const float*)d_in[10];
    const float* ar_neg = (const float*)d_in[11];
    const float* b_neg  = (const float*)d_in[12];
    const float* W1 = (const float*)d_in[13];
    const float* b1 = (const float*)d_in[14];
    const float* W2 = (const float*)d_in[15];
    const float* b2 = (const float*)d_in[16];

    const int n  = in_sizes[0] / 128;       // 100000
    const int ne = in_sizes[1];             // 600000
    const int nb = (n + 255) / 256;         // 391 blocks per half
    const int npad = nb * 256;              // 100096 (pos/neg halves 256-aligned)

    float* out  = (float*)d_out;
    float* hfin = out + (size_t)n * 256;

    // workspace layout (16B-aligned sections)
    unsigned short* featb = (unsigned short*)d_ws;        // [2n][128] bf16
    unsigned short* hcatb = featb + (size_t)2 * n * 128;  // [n][256] bf16
    unsigned short* mid   = hcatb + (size_t)n * 256;      // [n][128] bf16
    float* el_pos = (float*)(mid + (size_t)n * 128);
    float* er_pos = el_pos + (size_t)n * 8;
    float* el_neg = er_pos + (size_t)n * 8;
    float* er_neg = el_neg + (size_t)n * 8;
    unsigned short* Wcat = (unsigned short*)(er_neg + (size_t)n * 8);  // 256*128
    unsigned short* W1t  = Wcat + 256 * 128;                           // 128*256
    unsigned short* W2t  = W1t + 128 * 256;                            // 64*128
    int* cnt      = (int*)(W2t + 64 * 128);   // 2*npad (pos half | neg half)
    int* offs_pos = cnt + 2 * npad;           // n+1
    int* offs_neg = offs_pos + (n + 1);       // n+1
    int* bsum     = offs_neg + (n + 1);       // 2*nb
    int* ssrc_pos = bsum + 2 * nb;            // ne
    int* ssrc_neg = ssrc_pos + ne;            // ne

    const int gm = (n + 127) / 128;
    const int ge2 = (2 * ne + 255) / 256;

    convert_w_kernel<<<(73728 + 255) / 256, 256, 0, stream>>>(W_pos, W_neg, W1, W2, Wcat, W1t, W2t);

    // CSR build (fused pos+neg)
    hipMemsetAsync(cnt, 0, sizeof(int) * 2 * (size_t)npad, stream);
    count_kernel<<<ge2, 256, 0, stream>>>(pos_dst, neg_dst, cnt, ne, npad);
    scan1_kernel<<<2 * nb, 256, 0, stream>>>(cnt, bsum);
    scan2_kernel<<<2, 512, 0, stream>>>(bsum, nb);
    scan3_kernel<<<2 * nb, 256, 0, stream>>>(cnt, bsum, offs_pos, offs_neg, n, ne, npad);
    scatter_kernel<<<ge2, 256, 0, stream>>>(pos_src, pos_dst, neg_src, neg_dst, cnt, ssrc_pos, ssrc_neg, ne, npad);

    // feat GEMM: fp32 A converted in staging; y=0 -> featb(pos), y=1 -> featb(neg); bf16 out
    mfma_gemm_kernel<128, 128, true, false, true><<<dim3(gm, 2), 256, 0, stream>>>(features, Wcat, nullptr, featb, n);

    eler_kernel<<<(2 * n * 8 + 255) / 256, 256, 0, stream>>>(featb, al_pos, ar_pos, al_neg, ar_neg,
                                                             el_pos, er_pos, el_neg, er_neg, n);

    gat_gather_kernel<<<dim3((n + 3) / 4, 2), 256, 0, stream>>>(offs_pos, offs_neg, ssrc_pos, ssrc_neg,
                                                                el_pos, er_pos, el_neg, er_neg,
                                                                featb, b_pos, b_neg, out, hcatb, n);

    // MLP (bf16 MFMA)
    mfma_gemm_kernel<256, 128, false, true, true><<<dim3(gm, 1), 256, 0, stream>>>(hcatb, W1t, b1, mid, n);
    mfma_gemm_kernel<128, 64, false, false, false><<<dim3(gm, 1), 256, 0, stream>>>(mid, W2t, b2, hfin, n);
}